// Round 1
// baseline (12.734 us; speedup 1.0000x reference)
//
#include <hip/hip_runtime.h>

// Reference collapses algebraically:
//   z = softmax(z, axis=0)        -> every column sums to exactly 1 over the G axis
//   z = z @ W2 + b2
//   return mean(z, axis=0)        -> mean over the SAME axis
// mean_r(S @ W2 + b2)[c] = sum_k (mean_r S[r,k]) W2[k,c] + b2[c]
//                        = (1/G) * sum_k W2[k,c] + b2[c]
// Every upstream input (x, edges, Cheb/TAG/Transformer weights, pooling)
// cancels exactly. Output depends only on W2, b2, and G.
__global__ void GNN_43035572305985_kernel(const float* __restrict__ W2,
                                          const float* __restrict__ b2,
                                          float* __restrict__ out,
                                          int K,        // rows of W2 (= OUT = 64)
                                          int C,        // cols of W2 / output size (= 64)
                                          float invG) { // 1.0f / G
    int c = blockIdx.x * blockDim.x + threadIdx.x;
    if (c < C) {
        float s = 0.0f;
        for (int k = 0; k < K; ++k) {
            s += W2[k * C + c];
        }
        out[c] = s * invG + b2[c];
    }
}

extern "C" void kernel_launch(void* const* d_in, const int* in_sizes, int n_in,
                              void* d_out, int out_size, void* d_ws, size_t ws_size,
                              hipStream_t stream) {
    // setup_inputs() dict order:
    //  0:x 1:edge_src 2:edge_dst 3:batch 4:root_n_id 5:Wc 6:bc 7:Wt 8:bt
    //  9:Wq 10:bq 11:Wk 12:bk 13:Wv 14:bv 15:Ws 16:bs 17:W1 18:b1 19:W2 20:b2
    const float* W2 = (const float*)d_in[19];
    const float* b2 = (const float*)d_in[20];
    float* out = (float*)d_out;

    const int C = out_size;                 // 64 output channels ([OUT,1] flat)
    const int K = in_sizes[19] / C;         // W2 is [K, C] row-major -> K = 64
    const int G = in_sizes[4];              // root_n_id has G entries -> G = 512
    const float invG = 1.0f / (float)G;

    dim3 grid((C + 63) / 64), block(64);
    hipLaunchKernelGGL(GNN_43035572305985_kernel, grid, block, 0, stream,
                       W2, b2, out, K, C, invG);
}